// Round 13
// baseline (126.275 us; speedup 1.0000x reference)
//
#include <hip/hip_runtime.h>
#include <hip/hip_bf16.h>
#include <math.h>

#define N_ROWS 8192
#define DIM 1024
#define DIMB 1024         // bytes per int8 row
#define BM 128
#define BN 128
#define BKB 128           // K-tile in BYTES (=128 int8 elems = 2 MFMA k-steps)
#define NT (DIMB / BKB)   // 8 K-tiles
#define NTILE 64          // 8192/128 tile grid
#define NBLK 2080         // 64*65/2 upper-triangle tiles

typedef __attribute__((ext_vector_type(4))) int i32x4;

__device__ __forceinline__ unsigned pk4(float4 v, float f) {
    float c0 = fmaxf(-127.f, fminf(127.f, v.x * f));
    float c1 = fmaxf(-127.f, fminf(127.f, v.y * f));
    float c2 = fmaxf(-127.f, fminf(127.f, v.z * f));
    float c3 = fmaxf(-127.f, fminf(127.f, v.w * f));
    int b0 = (int)rintf(c0), b1 = (int)rintf(c1);
    int b2 = (int)rintf(c2), b3 = (int)rintf(c3);
    return (unsigned)(b0 & 0xFF) | ((unsigned)(b1 & 0xFF) << 8) |
           ((unsigned)(b2 & 0xFF) << 16) | ((unsigned)(b3 & 0xFF) << 24);
}

// ---------------- Kernel 1: row L2-normalize fp32 -> per-row-scaled int8 ----------------
__global__ __launch_bounds__(256) void cl_norm_kernel(
    const float* __restrict__ z, signed char* __restrict__ zq, float* __restrict__ qs) {
    const int row  = blockIdx.x * 4 + (threadIdx.x >> 6);
    const int lane = threadIdx.x & 63;
    const float* zr = z + (size_t)row * DIM + lane * 16;
    float4 v[4];
    float ss = 0.f, am = 0.f;
#pragma unroll
    for (int j = 0; j < 4; ++j) {
        v[j] = *reinterpret_cast<const float4*>(zr + j * 4);
        ss += v[j].x * v[j].x + v[j].y * v[j].y + v[j].z * v[j].z + v[j].w * v[j].w;
        am = fmaxf(am, fmaxf(fmaxf(fabsf(v[j].x), fabsf(v[j].y)),
                             fmaxf(fabsf(v[j].z), fabsf(v[j].w))));
    }
#pragma unroll
    for (int m = 1; m < 64; m <<= 1) {
        ss += __shfl_xor(ss, m, 64);
        am = fmaxf(am, __shfl_xor(am, m, 64));
    }
    const float scale = 1.0f / fmaxf(sqrtf(ss), 1e-8f);
    const float amax  = am * scale;
    if (lane == 0) qs[row] = amax * (1.0f / 127.0f);
    const float f = (amax > 0.f) ? scale * (127.0f / amax) : 0.f;
    uint4 o;
    o.x = pk4(v[0], f);
    o.y = pk4(v[1], f);
    o.z = pk4(v[2], f);
    o.w = pk4(v[3], f);
    *reinterpret_cast<uint4*>(zq + (size_t)row * DIMB + lane * 16) = o;
}

// ---------------- Kernel 2: symmetric triangle int8 GEMM + dual partial LSE ----------------
// 128x128 tiles, 2080 upper-triangle blocks, 256 threads (4 waves, 2x2), 64KB LDS
// -> 2 blocks/CU for cross-block TLP (independent barriers hide each other's stalls).
// Round = 32 rows x 128 B = 4 KB staged by 256 thr x 16 B global_load_lds.
// Swizzle (rule #21): linear LDS dest + inverse-swizzled global source; reads
// XOR the same (row&7)<<4 mask.
__device__ __forceinline__ void stage_round(
    const signed char* __restrict__ zq, int g_row0, int k0,
    char* lds_round_base, int t) {
    const int r  = t >> 3;             // row within round (0..31)
    const int ch = (t & 7) ^ (r & 7);  // pre-swizzled 16B chunk of the 128B row-slice
    const signed char* src = zq + (size_t)(g_row0 + r) * DIMB + k0 + ch * 16;
    __builtin_amdgcn_global_load_lds(
        (const __attribute__((address_space(1))) void*)src,
        (__attribute__((address_space(3))) void*)(lds_round_base + t * 16), 16, 0, 0);
}

__device__ __forceinline__ i32x4 ld_frag(const char* tile, int row, int kbyte, int xm) {
    return *reinterpret_cast<const i32x4*>(tile + row * 128 + (kbyte ^ xm));
}

#define MFMAI8(a, b, c) __builtin_amdgcn_mfma_i32_16x16x64_i8((a), (b), (c), 0, 0, 0)

__global__ __launch_bounds__(256, 2) void cl_simlse8_kernel(
    const signed char* __restrict__ zq, const float* __restrict__ qs,
    float2* __restrict__ part,  // [128 chunks][8192 rows]
    float* __restrict__ pos) {  // [8192]
    extern __shared__ char smem[];  // 64 KB: A0@0, B0@16K, A1@32K, B1@48K

    const int t    = threadIdx.x;
    const int lane = t & 63;
    const int wid  = t >> 6;   // 0..3
    const int wr   = wid >> 1; // 0..1 (M)
    const int wc   = wid & 1;  // 0..1 (N)
    const int l15  = lane & 15;
    const int xm   = (lane & 7) << 4;        // read-side swizzle mask ((row&7)<<4)
    const int kq16 = ((lane >> 4) & 3) * 16; // k sub-chunk byte offset
    const float invT = 1.0f / 0.07f;

    // triangle decode with XCD chunking: 2080 = 8 * 260 (bijective)
    const int id2 = (blockIdx.x & 7) * 260 + (blockIdx.x >> 3);
    int ri = 0, rem = id2;
    while (rem >= NTILE - ri) { rem -= NTILE - ri; ++ri; }
    const int ci = ri + rem;  // ri <= ci
    const int rbase = ri * BM;
    const int cbase = ci * BN;

    const i32x4 zero4 = {0, 0, 0, 0};
    i32x4 acc[4][4];
#pragma unroll
    for (int m = 0; m < 4; ++m)
#pragma unroll
        for (int n = 0; n < 4; ++n) acc[m][n] = zero4;

    i32x4 a4[4], b4[4];  // one k-step's fragments (re-read per phase)

    // ---- prologue: stage tile 0 (A 4 rounds + B 4 rounds) ----
    {
        char* A0b = smem;
        char* B0b = smem + 16384;
        stage_round(zq, rbase + 0,  0, A0b + 0,     t);
        stage_round(zq, rbase + 32, 0, A0b + 4096,  t);
        stage_round(zq, rbase + 64, 0, A0b + 8192,  t);
        stage_round(zq, rbase + 96, 0, A0b + 12288, t);
        stage_round(zq, cbase + 0,  0, B0b + 0,     t);
        stage_round(zq, cbase + 32, 0, B0b + 4096,  t);
        stage_round(zq, cbase + 64, 0, B0b + 8192,  t);
        stage_round(zq, cbase + 96, 0, B0b + 12288, t);
        asm volatile("s_waitcnt vmcnt(0)" ::: "memory");
        __builtin_amdgcn_sched_barrier(0);
        __builtin_amdgcn_s_barrier();
    }

    // ---- main loop: 2 phases per K-tile; stage (kt+1) during phA ----
    for (int kt = 0; kt < NT; ++kt) {
        const int c = kt & 1;
        char* curA = smem + c * 32768;
        char* curB = curA + 16384;
        char* nxtA = smem + (c ^ 1) * 32768;
        char* nxtB = nxtA + 16384;
        const int k1 = (kt + 1) * BKB;

        // ---- phase A: read A-k0 (4) + B-k0 (4); stage (kt+1) A+B (8 rounds); MFMA k0 ----
#pragma unroll
        for (int mi = 0; mi < 4; ++mi)
            a4[mi] = ld_frag(curA, wr * 64 + mi * 16 + l15, kq16, xm);
#pragma unroll
        for (int nf = 0; nf < 4; ++nf)
            b4[nf] = ld_frag(curB, wc * 64 + nf * 16 + l15, kq16, xm);
        if (kt + 1 < NT) {  // nxt buffers fully read by (kt-1)'s final barrier
            stage_round(zq, rbase + 0,  k1, nxtA + 0,     t);
            stage_round(zq, rbase + 32, k1, nxtA + 4096,  t);
            stage_round(zq, rbase + 64, k1, nxtA + 8192,  t);
            stage_round(zq, rbase + 96, k1, nxtA + 12288, t);
            stage_round(zq, cbase + 0,  k1, nxtB + 0,     t);
            stage_round(zq, cbase + 32, k1, nxtB + 4096,  t);
            stage_round(zq, cbase + 64, k1, nxtB + 8192,  t);
            stage_round(zq, cbase + 96, k1, nxtB + 12288, t);
        }
        __builtin_amdgcn_s_barrier();
        asm volatile("s_waitcnt lgkmcnt(0)" ::: "memory");
        __builtin_amdgcn_sched_barrier(0);
        __builtin_amdgcn_s_setprio(1);
#pragma unroll
        for (int mi = 0; mi < 4; ++mi)
#pragma unroll
            for (int nf = 0; nf < 4; ++nf)
                acc[mi][nf] = MFMAI8(a4[mi], b4[nf], acc[mi][nf]);
        __builtin_amdgcn_s_setprio(0);
        __builtin_amdgcn_s_barrier();

        // ---- phase B: read A-k1 (4) + B-k1 (4); MFMA k1; boundary drain ----
#pragma unroll
        for (int mi = 0; mi < 4; ++mi)
            a4[mi] = ld_frag(curA, wr * 64 + mi * 16 + l15, 64 + kq16, xm);
#pragma unroll
        for (int nf = 0; nf < 4; ++nf)
            b4[nf] = ld_frag(curB, wc * 64 + nf * 16 + l15, 64 + kq16, xm);
        __builtin_amdgcn_s_barrier();
        asm volatile("s_waitcnt lgkmcnt(0)" ::: "memory");
        __builtin_amdgcn_sched_barrier(0);
        __builtin_amdgcn_s_setprio(1);
#pragma unroll
        for (int mi = 0; mi < 4; ++mi)
#pragma unroll
            for (int nf = 0; nf < 4; ++nf)
                acc[mi][nf] = MFMAI8(a4[mi], b4[nf], acc[mi][nf]);
        __builtin_amdgcn_s_setprio(0);
        if (kt + 1 < NT) {
            asm volatile("s_waitcnt vmcnt(0)" ::: "memory");  // (kt+1) staged & landed
            __builtin_amdgcn_sched_barrier(0);
        }
        __builtin_amdgcn_s_barrier();
    }

    // ---- epilogue A: row partials (dequant: logit = acc * qs[r] * qs[c] / T) ----
    const int chunk = ci * 2 + wc;
    float qc[4];
#pragma unroll
    for (int nf = 0; nf < 4; ++nf)
        qc[nf] = qs[cbase + wc * 64 + nf * 16 + l15] * invT;
#pragma unroll
    for (int mi = 0; mi < 4; ++mi) {
#pragma unroll
        for (int reg = 0; reg < 4; ++reg) {
            const int grow = rbase + wr * 64 + mi * 16 + (lane >> 4) * 4 + reg;
            const int posj = (grow - 4096) & (N_ROWS - 1);
            const float qr = qs[grow];
            float vals[4];
            float rmax = -3.4e38f;
#pragma unroll
            for (int nf = 0; nf < 4; ++nf) {
                const int gcol = cbase + wc * 64 + nf * 16 + l15;
                float logit = (float)acc[mi][nf][reg] * qr * qc[nf];
                if (gcol == grow) logit = -9e15f * invT;  // diag mask (diag tiles only)
                if (gcol == posj) {
                    pos[grow] = logit;   // involution: pair covered once, both sides
                    pos[gcol] = logit;
                }
                vals[nf] = logit;
                rmax = fmaxf(rmax, logit);
            }
#pragma unroll
            for (int msk = 1; msk < 16; msk <<= 1)
                rmax = fmaxf(rmax, __shfl_xor(rmax, msk, 64));
            float s = 0.f;
#pragma unroll
            for (int nf = 0; nf < 4; ++nf) s += __expf(vals[nf] - rmax);
#pragma unroll
            for (int msk = 1; msk < 16; msk <<= 1) s += __shfl_xor(s, msk, 64);
            if (l15 == 0) {
                part[(size_t)chunk * N_ROWS + grow] = make_float2(rmax, s);
            }
        }
    }

    // ---- epilogue B: column partials (transpose rows) — off-diag only ----
    if (ri != ci) {
        const int chunkT = ri * 2 + wr;
        float qrow[4][4];
#pragma unroll
        for (int mi = 0; mi < 4; ++mi)
#pragma unroll
            for (int reg = 0; reg < 4; ++reg)
                qrow[mi][reg] = qs[rbase + wr * 64 + mi * 16 + (lane >> 4) * 4 + reg] * invT;
#pragma unroll
        for (int nf = 0; nf < 4; ++nf) {
            const int gcol = cbase + wc * 64 + nf * 16 + l15;
            const float qcg = qs[gcol];
            float cmax = -3.4e38f;
#pragma unroll
            for (int mi = 0; mi < 4; ++mi)
#pragma unroll
                for (int reg = 0; reg < 4; ++reg)
                    cmax = fmaxf(cmax, (float)acc[mi][nf][reg] * qrow[mi][reg] * qcg);
            cmax = fmaxf(cmax, __shfl_xor(cmax, 16, 64));
            cmax = fmaxf(cmax, __shfl_xor(cmax, 32, 64));
            float cs = 0.f;
#pragma unroll
            for (int mi = 0; mi < 4; ++mi)
#pragma unroll
                for (int reg = 0; reg < 4; ++reg)
                    cs += __expf((float)acc[mi][nf][reg] * qrow[mi][reg] * qcg - cmax);
            cs += __shfl_xor(cs, 16, 64);
            cs += __shfl_xor(cs, 32, 64);
            if (lane < 16) {
                part[(size_t)chunkT * N_ROWS + gcol] = make_float2(cmax, cs);
            }
        }
    }
}

// ---------------- Kernel 3: combine partials -> per-block nll sums ----------------
__global__ __launch_bounds__(256) void cl_combine_kernel(
    const float2* __restrict__ part, const float* __restrict__ pos,
    float* __restrict__ bsum) {
    const int r = blockIdx.x * 256 + threadIdx.x;
    float M = -3.4e38f;
#pragma unroll 8
    for (int c = 0; c < 128; ++c) M = fmaxf(M, part[(size_t)c * N_ROWS + r].x);
    float L = 0.f;
#pragma unroll 8
    for (int c = 0; c < 128; ++c) {
        const float2 p = part[(size_t)c * N_ROWS + r];
        L += p.y * __expf(p.x - M);
    }
    float nll = M + logf(L) - pos[r];
    __shared__ float red[4];
#pragma unroll
    for (int msk = 1; msk < 64; msk <<= 1) nll += __shfl_xor(nll, msk, 64);
    if ((threadIdx.x & 63) == 0) red[threadIdx.x >> 6] = nll;
    __syncthreads();
    if (threadIdx.x == 0) bsum[blockIdx.x] = red[0] + red[1] + red[2] + red[3];
}

// ---------------- Kernel 4: final mean ----------------
__global__ void cl_final_kernel(const float* __restrict__ bsum, float* __restrict__ out) {
    const int lane = threadIdx.x;
    float v = (lane < 32) ? bsum[lane] : 0.f;
#pragma unroll
    for (int msk = 1; msk < 64; msk <<= 1) v += __shfl_xor(v, msk, 64);
    if (lane == 0) out[0] = v * (1.0f / (float)N_ROWS);
}

extern "C" void kernel_launch(void* const* d_in, const int* in_sizes, int n_in,
                              void* d_out, int out_size, void* d_ws, size_t ws_size,
                              hipStream_t stream) {
    const float* z = (const float*)d_in[0];
    float* out = (float*)d_out;

    uint8_t* ws = (uint8_t*)d_ws;
    signed char* zq = (signed char*)ws;                        //  8 MB
    float2* part = (float2*)(ws + ((size_t)8 << 20));          //  8 MB
    float* pos   = (float*)(ws + ((size_t)16 << 20));          // 32 KB
    float* qs    = (float*)(ws + ((size_t)16 << 20) + 32768);  // 32 KB
    float* bsum  = (float*)(ws + ((size_t)16 << 20) + 65536);  // 128 B

    (void)hipFuncSetAttribute((const void*)cl_simlse8_kernel,
                              hipFuncAttributeMaxDynamicSharedMemorySize, 65536);

    cl_norm_kernel<<<N_ROWS / 4, 256, 0, stream>>>(z, zq, qs);
    cl_simlse8_kernel<<<NBLK, 256, 65536, stream>>>(zq, qs, part, pos);  // upper triangle
    cl_combine_kernel<<<N_ROWS / 256, 256, 0, stream>>>(part, pos, bsum);
    cl_final_kernel<<<1, 64, 0, stream>>>(bsum, out);
}